// Round 14
// baseline (332.753 us; speedup 1.0000x reference)
//
#include <hip/hip_runtime.h>
#include <hip/hip_fp16.h>
#include <math.h>

#define NPTS   (1u << 20)
#define NLVL   16
#define NLDS   3                 // levels 0..2 from LDS-resident grids
#define NGRID  5                 // levels 0..4 dense fp16 grids (2.1 MB total)
#define TBITS  19
#define TSIZE  (1u << TBITS)
#define TMASK  (TSIZE - 1u)
#define CHUNKS (NPTS / 256u)     // 4096 blocks per level-phase
#define NMAIN  (NLVL - NLDS)     // 13 phased levels (3..15)
#define PR1    2654435761u
#define PR2    805459861u

typedef float vf4 __attribute__((ext_vector_type(4)));

struct Params {
    float    s[NLVL];
    uint32_t gdim[NGRID];
    uint32_t goff[NGRID];        // __half2 offset of each grid in gridbuf
    uint32_t vcum[NGRID + 1];
};

__device__ __forceinline__ float2 h2f_bits(float bits)
{
    __half2 h; __builtin_memcpy(&h, &bits, 4);
    return __half22float2(h);
}
__device__ __forceinline__ float2 h2f_u32(uint32_t u)
{
    __half2 h; __builtin_memcpy(&h, &u, 4);
    return __half22float2(h);
}

// ---------------------------------------------------------------------------
// fp16-table pair issue, sc0 (L1-bypass). One vmcnt(0)+sched_barrier before
// consumption (rule #18).
// ---------------------------------------------------------------------------
__device__ __forceinline__ void issue_pair_h(const __half2* __restrict__ t,
                                             uint32_t iF, uint32_t iC,
                                             float2& q, float& a, float& b,
                                             bool& merged, bool& swp)
{
    const uint32_t lo = iF < iC ? iF : iC;
    const uint32_t hi = iF < iC ? iC : iF;
    merged = (hi - lo == 1u);
    swp    = merged && (iF == hi);
    if (merged) {
        asm volatile("global_load_dwordx2 %0, %1, off sc0"
                     : "=v"(q) : "v"(t + lo));
    } else {
        asm volatile("global_load_dword %0, %1, off sc0"
                     : "=v"(a) : "v"(t + iF));
        asm volatile("global_load_dword %0, %1, off sc0"
                     : "=v"(b) : "v"(t + iC));
    }
}

__device__ __forceinline__ float2 sel_Fh(const float2& q, float a, bool m, bool s)
{ return m ? h2f_bits(s ? q.y : q.x) : h2f_bits(a); }
__device__ __forceinline__ float2 sel_Ch(const float2& q, float b, bool m, bool s)
{ return m ? h2f_bits(s ? q.x : q.y) : h2f_bits(b); }

// Shared trilinear tail (same op order as the reference).
__device__ __forceinline__ float2 lerp8(float2 f0, float2 f1, float2 f2, float2 f3,
                                        float2 f4, float2 f5, float2 f6, float2 f7,
                                        float ox, float oy, float oz)
{
    const float omx = 1.0f - ox, omy = 1.0f - oy, omz = 1.0f - oz;
    const float a0 = f0.x * ox + f3.x * omx, b0 = f0.y * ox + f3.y * omx;
    const float a1 = f1.x * ox + f2.x * omx, b1 = f1.y * ox + f2.y * omx;
    const float a2 = f5.x * ox + f6.x * omx, b2 = f5.y * ox + f6.y * omx;
    const float a3 = f4.x * ox + f7.x * omx, b3 = f4.y * ox + f7.y * omx;
    const float c0 = a0 * oy + a1 * omy, d0 = b0 * oy + b1 * omy;
    const float c1 = a3 * oy + a2 * omy, d1 = b3 * oy + b2 * omy;
    return make_float2(c0 * oz + c1 * omz, d0 * oz + d1 * omz);
}

// Hash-table evaluation (fp16 table, sc0 gathers).
__device__ __forceinline__ float2 eval_hash_h(float x0, float x1, float x2,
                                              float s, uint32_t l,
                                              const __half2* __restrict__ th)
{
    const float sx = x0 * s, sy = x1 * s, sz = x2 * s;
    const float fxf = floorf(sx), fyf = floorf(sy), fzf = floorf(sz);
    const float cxf = ceilf(sx),  cyf = ceilf(sy),  czf = ceilf(sz);
    const float ox = sx - fxf, oy = sy - fyf, oz = sz - fzf;

    const uint32_t fx = (uint32_t)fxf, cx = (uint32_t)cxf;
    const uint32_t Yf = (uint32_t)fyf * PR1,  Yc = (uint32_t)cyf * PR1;
    const uint32_t Zf = (uint32_t)fzf * PR2,  Zc = (uint32_t)czf * PR2;
    const uint32_t base = l << TBITS;

    const uint32_t i0 = ((cx ^ Yc ^ Zc) & TMASK) + base;
    const uint32_t i1 = ((cx ^ Yf ^ Zc) & TMASK) + base;
    const uint32_t i2 = ((fx ^ Yf ^ Zc) & TMASK) + base;
    const uint32_t i3 = ((fx ^ Yc ^ Zc) & TMASK) + base;
    const uint32_t i4 = ((cx ^ Yc ^ Zf) & TMASK) + base;
    const uint32_t i5 = ((cx ^ Yf ^ Zf) & TMASK) + base;
    const uint32_t i6 = ((fx ^ Yf ^ Zf) & TMASK) + base;
    const uint32_t i7 = ((fx ^ Yc ^ Zf) & TMASK) + base;

    float2 qA, qB, qC, qD;
    float aA, bA, aB, bB, aC, bC, aD, bD;
    bool mA, sA, mB, sB, mC, sC, mD, sD;
    issue_pair_h(th, i3, i0, qA, aA, bA, mA, sA);
    issue_pair_h(th, i2, i1, qB, aB, bB, mB, sB);
    issue_pair_h(th, i7, i4, qC, aC, bC, mC, sC);
    issue_pair_h(th, i6, i5, qD, aD, bD, mD, sD);
    asm volatile("s_waitcnt vmcnt(0)" ::: "memory");
    __builtin_amdgcn_sched_barrier(0);

    const float2 f3 = sel_Fh(qA, aA, mA, sA), f0 = sel_Ch(qA, bA, mA, sA);
    const float2 f2 = sel_Fh(qB, aB, mB, sB), f1 = sel_Ch(qB, bB, mB, sB);
    const float2 f7 = sel_Fh(qC, aC, mC, sC), f4 = sel_Ch(qC, bC, mC, sC);
    const float2 f6 = sel_Fh(qD, aD, mD, sD), f5 = sel_Ch(qD, bD, mD, sD);
    return lerp8(f0, f1, f2, f3, f4, f5, f6, f7, ox, oy, oz);
}

// Dense fp16-grid evaluation (global, levels 3..4).
__device__ __forceinline__ float2 eval_grid_h(float x0, float x1, float x2,
                                              float s,
                                              const __half2* __restrict__ g,
                                              uint32_t d)
{
    const float sx = x0 * s, sy = x1 * s, sz = x2 * s;
    const float fxf = floorf(sx), fyf = floorf(sy), fzf = floorf(sz);
    const float cxf = ceilf(sx),  cyf = ceilf(sy),  czf = ceilf(sz);
    const float ox = sx - fxf, oy = sy - fyf, oz = sz - fzf;

    const uint32_t fx = (uint32_t)fxf, fy = (uint32_t)fyf, fz = (uint32_t)fzf;
    const uint32_t cy = (uint32_t)cyf, cz = (uint32_t)czf;
    const bool xadj = ((uint32_t)cxf == fx + 1u);

    const uint32_t bA = (cz * d + cy) * d + fx;
    const uint32_t bB = (cz * d + fy) * d + fx;
    const uint32_t bC = (fz * d + cy) * d + fx;
    const uint32_t bD = (fz * d + fy) * d + fx;

    float2 qA, qB, qC, qD;
    asm volatile("global_load_dwordx2 %0, %1, off sc0" : "=v"(qA) : "v"(g + bA));
    asm volatile("global_load_dwordx2 %0, %1, off sc0" : "=v"(qB) : "v"(g + bB));
    asm volatile("global_load_dwordx2 %0, %1, off sc0" : "=v"(qC) : "v"(g + bC));
    asm volatile("global_load_dwordx2 %0, %1, off sc0" : "=v"(qD) : "v"(g + bD));
    asm volatile("s_waitcnt vmcnt(0)" ::: "memory");
    __builtin_amdgcn_sched_barrier(0);

    const float2 f3 = h2f_bits(qA.x);
    const float2 f0 = xadj ? h2f_bits(qA.y) : f3;
    const float2 f2 = h2f_bits(qB.x);
    const float2 f1 = xadj ? h2f_bits(qB.y) : f2;
    const float2 f7 = h2f_bits(qC.x);
    const float2 f4 = xadj ? h2f_bits(qC.y) : f7;
    const float2 f6 = h2f_bits(qD.x);
    const float2 f5 = xadj ? h2f_bits(qD.y) : f6;
    return lerp8(f0, f1, f2, f3, f4, f5, f6, f7, ox, oy, oz);
}

// ------------------ LDS-resident grid kernels (levels 0..2) ----------------
// D = vertices/axis, PB = points per block. Copy grid into LDS once, then
// evaluate PB points per block with ZERO global gather requests.
template<int D, int PB>
__global__ __launch_bounds__(256)
void lds_grid_kernel(const float* __restrict__ x,
                     const __half2* __restrict__ gridsrc,   // this level's grid
                     __half2* __restrict__ stage,           // + l*NPTS
                     float s)
{
    __shared__ uint32_t lut[D * D * D];
    const uint32_t nv = (uint32_t)(D * D * D);
    const uint32_t* src = (const uint32_t*)gridsrc;
    for (uint32_t i = threadIdx.x; i < nv; i += 256u) lut[i] = src[i];
    __syncthreads();

    const uint32_t p0 = blockIdx.x * (uint32_t)PB;
    #pragma unroll
    for (int k = 0; k < PB / 256; ++k) {
        const uint32_t p = p0 + (uint32_t)k * 256u + threadIdx.x;
        const float x0 = x[p * 3 + 0];
        const float x1 = x[p * 3 + 1];
        const float x2 = x[p * 3 + 2];

        const float sx = x0 * s, sy = x1 * s, sz = x2 * s;
        const float fxf = floorf(sx), fyf = floorf(sy), fzf = floorf(sz);
        const float cxf = ceilf(sx),  cyf = ceilf(sy),  czf = ceilf(sz);
        const float ox = sx - fxf, oy = sy - fyf, oz = sz - fzf;

        const uint32_t fx = (uint32_t)fxf, fy = (uint32_t)fyf, fz = (uint32_t)fzf;
        const uint32_t cy = (uint32_t)cyf, cz = (uint32_t)czf;
        const uint32_t xo = ((uint32_t)cxf == fx + 1u) ? 1u : 0u;

        const uint32_t bA = (cz * D + cy) * D + fx;
        const uint32_t bB = (cz * D + fy) * D + fx;
        const uint32_t bC = (fz * D + cy) * D + fx;
        const uint32_t bD = (fz * D + fy) * D + fx;

        const float2 f3 = h2f_u32(lut[bA]);
        const float2 f0 = xo ? h2f_u32(lut[bA + 1]) : f3;
        const float2 f2 = h2f_u32(lut[bB]);
        const float2 f1 = xo ? h2f_u32(lut[bB + 1]) : f2;
        const float2 f7 = h2f_u32(lut[bC]);
        const float2 f4 = xo ? h2f_u32(lut[bC + 1]) : f7;
        const float2 f6 = h2f_u32(lut[bD]);
        const float2 f5 = xo ? h2f_u32(lut[bD + 1]) : f6;

        const float2 e = lerp8(f0, f1, f2, f3, f4, f5, f6, f7, ox, oy, oz);
        stage[p] = __floats2half2_rn(e.x, e.y);
    }
}

// --------------------- fp32 table -> fp16 table conversion -----------------
__global__ __launch_bounds__(256)
void convert_table(const float2* __restrict__ t, __half2* __restrict__ th)
{
    const uint32_t i = (blockIdx.x * 256u + threadIdx.x) * 4u;
    const float4 q0 = *(const float4*)(t + i);
    const float4 q1 = *(const float4*)(t + i + 2);
    __half2 h0 = __floats2half2_rn(q0.x, q0.y);
    __half2 h1 = __floats2half2_rn(q0.z, q0.w);
    __half2 h2 = __floats2half2_rn(q1.x, q1.y);
    __half2 h3 = __floats2half2_rn(q1.z, q1.w);
    uint32_t u0, u1, u2, u3;
    __builtin_memcpy(&u0, &h0, 4); __builtin_memcpy(&u1, &h1, 4);
    __builtin_memcpy(&u2, &h2, 4); __builtin_memcpy(&u3, &h3, 4);
    uint4 v; v.x = u0; v.y = u1; v.z = u2; v.w = u3;
    *(uint4*)(th + i) = v;
}

// ----------------------- dense fp16-grid build (levels 0..4) ---------------
__global__ __launch_bounds__(256)
void build_grids(const float2* __restrict__ table, __half2* __restrict__ gridbuf,
                 Params P)
{
    const uint32_t t = blockIdx.x * 256u + threadIdx.x;
    if (t >= P.vcum[NGRID]) return;
    uint32_t l = 0;
    #pragma unroll
    for (int i = 1; i < NGRID; ++i) if (t >= P.vcum[i]) l = i;
    const uint32_t v = t - P.vcum[l];
    const uint32_t d = P.gdim[l];
    const uint32_t vz = v / (d * d);
    const uint32_t r1 = v - vz * d * d;
    const uint32_t vy = r1 / d;
    const uint32_t vx = r1 - vy * d;
    const uint32_t h = ((vx ^ (vy * PR1) ^ (vz * PR2)) & TMASK) + (l << TBITS);
    const float2 e = table[h];
    gridbuf[P.goff[l] + v] = __floats2half2_rn(e.x, e.y);
}

// ------------- phased gather: levels 3..15 (grid 3..4 + hash 5..15) --------
__global__ __launch_bounds__(256)
void gather16(const float* __restrict__ x,
              const __half2* __restrict__ th,
              const __half2* __restrict__ gridbuf,
              __half2* __restrict__ stage,
              Params P)
{
    const uint32_t l = NLDS + blockIdx.x / CHUNKS;   // 3..15, level-phased
    const uint32_t p = (blockIdx.x % CHUNKS) * 256u + threadIdx.x;

    const float x0 = x[p * 3 + 0];
    const float x1 = x[p * 3 + 1];
    const float x2 = x[p * 3 + 2];

    float2 e;
    if (l < NGRID)
        e = eval_grid_h(x0, x1, x2, P.s[l], gridbuf + P.goff[l], P.gdim[l]);
    else
        e = eval_hash_h(x0, x1, x2, P.s[l], l, th);

    stage[l * NPTS + p] = __floats2half2_rn(e.x, e.y);
}

// ------------- transpose [l][p] -> [p][l], identity order, coalesced -------
__global__ __launch_bounds__(256)
void transpose_kernel(const __half2* __restrict__ stage, float* __restrict__ out)
{
    const uint32_t e = blockIdx.x * 256u + threadIdx.x;  // = p*8 + j
    const uint32_t p = e >> 3;
    const uint32_t j = e & 7u;
    const float2 a = __half22float2(stage[(2u*j)     * NPTS + p]);
    const float2 b = __half22float2(stage[(2u*j + 1) * NPTS + p]);
    vf4 v; v.x = a.x; v.y = a.y; v.z = b.x; v.w = b.y;
    __builtin_nontemporal_store(v, (vf4*)(out + (size_t)e * 4u));
}

// ------------------------- fused fallback (plain C++, fp32) ----------------
__device__ __forceinline__ void load_pair_plain(const float2* __restrict__ t,
                                                uint32_t iF, uint32_t iC,
                                                float2& vF, float2& vC)
{
    const uint32_t lo = iF < iC ? iF : iC;
    const uint32_t hi = iF < iC ? iC : iF;
    if (hi - lo == 1u) {
        const float4 q = *(const float4*)(t + lo);
        if (iF == lo) { vF = make_float2(q.x, q.y); vC = make_float2(q.z, q.w); }
        else          { vF = make_float2(q.z, q.w); vC = make_float2(q.x, q.y); }
    } else {
        vF = t[iF]; vC = t[iC];
    }
}

__global__ __launch_bounds__(256)
void hashenc_fused(const float* __restrict__ x,
                   const float2* __restrict__ table,
                   float2* __restrict__ out,
                   Params P)
{
    const uint32_t tid = blockIdx.x * 256u + threadIdx.x;
    const uint32_t p = tid >> 4;
    const uint32_t l = tid & 15u;

    const float x0 = x[p*3+0], x1 = x[p*3+1], x2 = x[p*3+2];
    const float s  = P.s[l];
    const float sx = x0 * s, sy = x1 * s, sz = x2 * s;
    const float fxf = floorf(sx), fyf = floorf(sy), fzf = floorf(sz);
    const float cxf = ceilf(sx),  cyf = ceilf(sy),  czf = ceilf(sz);
    const float ox = sx - fxf, oy = sy - fyf, oz = sz - fzf;

    const uint32_t fx = (uint32_t)fxf, cx = (uint32_t)cxf;
    const uint32_t Yf = (uint32_t)fyf * PR1,  Yc = (uint32_t)cyf * PR1;
    const uint32_t Zf = (uint32_t)fzf * PR2,  Zc = (uint32_t)czf * PR2;
    const uint32_t base = l << TBITS;

    const uint32_t i0 = ((cx ^ Yc ^ Zc) & TMASK) + base;
    const uint32_t i1 = ((cx ^ Yf ^ Zc) & TMASK) + base;
    const uint32_t i2 = ((fx ^ Yf ^ Zc) & TMASK) + base;
    const uint32_t i3 = ((fx ^ Yc ^ Zc) & TMASK) + base;
    const uint32_t i4 = ((cx ^ Yc ^ Zf) & TMASK) + base;
    const uint32_t i5 = ((cx ^ Yf ^ Zf) & TMASK) + base;
    const uint32_t i6 = ((fx ^ Yf ^ Zf) & TMASK) + base;
    const uint32_t i7 = ((fx ^ Yc ^ Zf) & TMASK) + base;

    float2 f0, f1, f2, f3, f4, f5, f6, f7;
    load_pair_plain(table, i3, i0, f3, f0);
    load_pair_plain(table, i2, i1, f2, f1);
    load_pair_plain(table, i7, i4, f7, f4);
    load_pair_plain(table, i6, i5, f6, f5);
    out[p * 16u + l] = lerp8(f0, f1, f2, f3, f4, f5, f6, f7, ox, oy, oz);
}

extern "C" void kernel_launch(void* const* d_in, const int* in_sizes, int n_in,
                              void* d_out, int out_size, void* d_ws, size_t ws_size,
                              hipStream_t stream) {
    const float*  x     = (const float*)d_in[0];
    const float2* table = (const float2*)d_in[1];

    // SCALINGS: replicate numpy float64 pipeline in identical op order.
    Params P;
    const double growth = exp((log(4096.0) - log(16.0)) / 15.0);
    for (int l = 0; l < NLVL; ++l)
        P.s[l] = (float)floor(16.0 * pow(growth, (double)l));

    uint32_t vtot = 0;
    for (int l = 0; l < NGRID; ++l) {
        const uint32_t d = (uint32_t)P.s[l] + 1u;
        P.gdim[l] = d;
        P.vcum[l] = vtot;
        P.goff[l] = vtot;
        vtot += d * d * d;
    }
    P.vcum[NGRID] = vtot;                            // 533,601 vertices

    // ws: gridbuf_h (~2.1 MiB) | table_h (32 MiB) | stage fp16 (64 MiB)
    const size_t grid_bytes  = (((size_t)vtot * sizeof(__half2)) + 255u) & ~(size_t)255u;
    const size_t tabh_bytes  = (size_t)TSIZE * NLVL * sizeof(__half2);
    const size_t stage_bytes = (size_t)NPTS * NLVL * sizeof(__half2);
    const size_t ws_needed   = grid_bytes + tabh_bytes + stage_bytes;

    if (ws_size >= ws_needed && P.gdim[0] == 17u && P.gdim[1] == 24u && P.gdim[2] == 34u) {
        __half2* gridbuf = (__half2*)d_ws;
        __half2* th      = (__half2*)((char*)d_ws + grid_bytes);
        __half2* stage   = (__half2*)((char*)d_ws + grid_bytes + tabh_bytes);

        dim3 b256(256u);
        hipLaunchKernelGGL(convert_table, dim3(TSIZE * NLVL / 1024u), b256, 0, stream,
                           table, th);
        hipLaunchKernelGGL(build_grids, dim3((vtot + 255u) / 256u), b256, 0, stream,
                           table, gridbuf, P);
        // LDS-resident coarse levels (0..2): zero global gather requests.
        hipLaunchKernelGGL((lds_grid_kernel<17, 512>),  dim3(NPTS / 512u),  b256, 0, stream,
                           x, gridbuf + P.goff[0], stage + 0u * NPTS, P.s[0]);
        hipLaunchKernelGGL((lds_grid_kernel<24, 1024>), dim3(NPTS / 1024u), b256, 0, stream,
                           x, gridbuf + P.goff[1], stage + 1u * NPTS, P.s[1]);
        hipLaunchKernelGGL((lds_grid_kernel<34, 2048>), dim3(NPTS / 2048u), b256, 0, stream,
                           x, gridbuf + P.goff[2], stage + 2u * NPTS, P.s[2]);
        // Phased main gather: levels 3..15.
        hipLaunchKernelGGL(gather16, dim3(NMAIN * CHUNKS), b256, 0, stream,
                           x, th, gridbuf, stage, P);
        hipLaunchKernelGGL(transpose_kernel, dim3(NPTS * 8u / 256u), b256, 0, stream,
                           stage, (float*)d_out);
    } else {
        float2* out = (float2*)d_out;
        hipLaunchKernelGGL(hashenc_fused, dim3(NPTS * NLVL / 256u), dim3(256u), 0, stream,
                           x, table, out, P);
    }
}

// Round 15
// 318.397 us; speedup vs baseline: 1.0451x; 1.0451x over previous
//
#include <hip/hip_runtime.h>
#include <hip/hip_fp16.h>
#include <math.h>

#define NPTS   (1u << 20)
#define NLVL   16
#define NGRID  5                 // levels 0..4 via dense fp16 grids (2.1 MB total)
#define TBITS  19
#define TSIZE  (1u << TBITS)
#define TMASK  (TSIZE - 1u)
#define CHUNKS (NPTS / 256u)     // 4096 blocks per level-phase
#define PR1    2654435761u
#define PR2    805459861u

typedef float vf4 __attribute__((ext_vector_type(4)));

struct Params {
    float    s[NLVL];
    uint32_t gdim[NGRID];
    uint32_t goff[NGRID];        // __half2 offset of each grid in gridbuf_h
    uint32_t vcum[NGRID + 1];
};

// reinterpret 4 bytes (one __half2) -> float2
__device__ __forceinline__ float2 h2f_bits(float bits)
{
    __half2 h; __builtin_memcpy(&h, &bits, 4);
    return __half22float2(h);
}

// ---------------------------------------------------------------------------
// fp16-table pair issue, sc0 (L1-bypass). Adjacent pair (|iF-iC|==1) -> one
// 8B dwordx2 (both entries); else two 4B dwords. One vmcnt(0)+sched_barrier
// before consumption (rule #18).
// ---------------------------------------------------------------------------
__device__ __forceinline__ void issue_pair_h(const __half2* __restrict__ t,
                                             uint32_t iF, uint32_t iC,
                                             float2& q, float& a, float& b,
                                             bool& merged, bool& swp)
{
    const uint32_t lo = iF < iC ? iF : iC;
    const uint32_t hi = iF < iC ? iC : iF;
    merged = (hi - lo == 1u);
    swp    = merged && (iF == hi);
    if (merged) {
        asm volatile("global_load_dwordx2 %0, %1, off sc0"
                     : "=v"(q) : "v"(t + lo));
    } else {
        asm volatile("global_load_dword %0, %1, off sc0"
                     : "=v"(a) : "v"(t + iF));
        asm volatile("global_load_dword %0, %1, off sc0"
                     : "=v"(b) : "v"(t + iC));
    }
}

__device__ __forceinline__ float2 sel_Fh(const float2& q, float a, bool m, bool s)
{ return m ? h2f_bits(s ? q.y : q.x) : h2f_bits(a); }
__device__ __forceinline__ float2 sel_Ch(const float2& q, float b, bool m, bool s)
{ return m ? h2f_bits(s ? q.x : q.y) : h2f_bits(b); }

// Shared trilinear tail (same op order as the reference).
__device__ __forceinline__ float2 lerp8(float2 f0, float2 f1, float2 f2, float2 f3,
                                        float2 f4, float2 f5, float2 f6, float2 f7,
                                        float ox, float oy, float oz)
{
    const float omx = 1.0f - ox, omy = 1.0f - oy, omz = 1.0f - oz;
    const float a0 = f0.x * ox + f3.x * omx, b0 = f0.y * ox + f3.y * omx;
    const float a1 = f1.x * ox + f2.x * omx, b1 = f1.y * ox + f2.y * omx;
    const float a2 = f5.x * ox + f6.x * omx, b2 = f5.y * ox + f6.y * omx;
    const float a3 = f4.x * ox + f7.x * omx, b3 = f4.y * ox + f7.y * omx;
    const float c0 = a0 * oy + a1 * omy, d0 = b0 * oy + b1 * omy;
    const float c1 = a3 * oy + a2 * omy, d1 = b3 * oy + b2 * omy;
    return make_float2(c0 * oz + c1 * omz, d0 * oz + d1 * omz);
}

// Hash-table evaluation (levels >= NGRID), fp16 table, sc0 gathers.
__device__ __forceinline__ float2 eval_hash_h(float x0, float x1, float x2,
                                              float s, uint32_t l,
                                              const __half2* __restrict__ th)
{
    const float sx = x0 * s, sy = x1 * s, sz = x2 * s;
    const float fxf = floorf(sx), fyf = floorf(sy), fzf = floorf(sz);
    const float cxf = ceilf(sx),  cyf = ceilf(sy),  czf = ceilf(sz);
    const float ox = sx - fxf, oy = sy - fyf, oz = sz - fzf;

    const uint32_t fx = (uint32_t)fxf, cx = (uint32_t)cxf;
    const uint32_t Yf = (uint32_t)fyf * PR1,  Yc = (uint32_t)cyf * PR1;
    const uint32_t Zf = (uint32_t)fzf * PR2,  Zc = (uint32_t)czf * PR2;
    const uint32_t base = l << TBITS;

    const uint32_t i0 = ((cx ^ Yc ^ Zc) & TMASK) + base;
    const uint32_t i1 = ((cx ^ Yf ^ Zc) & TMASK) + base;
    const uint32_t i2 = ((fx ^ Yf ^ Zc) & TMASK) + base;
    const uint32_t i3 = ((fx ^ Yc ^ Zc) & TMASK) + base;
    const uint32_t i4 = ((cx ^ Yc ^ Zf) & TMASK) + base;
    const uint32_t i5 = ((cx ^ Yf ^ Zf) & TMASK) + base;
    const uint32_t i6 = ((fx ^ Yf ^ Zf) & TMASK) + base;
    const uint32_t i7 = ((fx ^ Yc ^ Zf) & TMASK) + base;

    float2 qA, qB, qC, qD;
    float aA, bA, aB, bB, aC, bC, aD, bD;
    bool mA, sA, mB, sB, mC, sC, mD, sD;
    issue_pair_h(th, i3, i0, qA, aA, bA, mA, sA);   // f3 (floor-x), f0 (ceil-x)
    issue_pair_h(th, i2, i1, qB, aB, bB, mB, sB);   // f2, f1
    issue_pair_h(th, i7, i4, qC, aC, bC, mC, sC);   // f7, f4
    issue_pair_h(th, i6, i5, qD, aD, bD, mD, sD);   // f6, f5
    asm volatile("s_waitcnt vmcnt(0)" ::: "memory");
    __builtin_amdgcn_sched_barrier(0);

    const float2 f3 = sel_Fh(qA, aA, mA, sA), f0 = sel_Ch(qA, bA, mA, sA);
    const float2 f2 = sel_Fh(qB, aB, mB, sB), f1 = sel_Ch(qB, bB, mB, sB);
    const float2 f7 = sel_Fh(qC, aC, mC, sC), f4 = sel_Ch(qC, bC, mC, sC);
    const float2 f6 = sel_Fh(qD, aD, mD, sD), f5 = sel_Ch(qD, bD, mD, sD);
    return lerp8(f0, f1, f2, f3, f4, f5, f6, f7, ox, oy, oz);
}

// Dense fp16-grid evaluation (levels < NGRID): x-pair = one 8B dwordx2.
__device__ __forceinline__ float2 eval_grid_h(float x0, float x1, float x2,
                                              float s,
                                              const __half2* __restrict__ g,
                                              uint32_t d)
{
    const float sx = x0 * s, sy = x1 * s, sz = x2 * s;
    const float fxf = floorf(sx), fyf = floorf(sy), fzf = floorf(sz);
    const float cxf = ceilf(sx),  cyf = ceilf(sy),  czf = ceilf(sz);
    const float ox = sx - fxf, oy = sy - fyf, oz = sz - fzf;

    const uint32_t fx = (uint32_t)fxf, fy = (uint32_t)fyf, fz = (uint32_t)fzf;
    const uint32_t cy = (uint32_t)cyf, cz = (uint32_t)czf;
    const bool xadj = ((uint32_t)cxf == fx + 1u);

    const uint32_t bA = (cz * d + cy) * d + fx;
    const uint32_t bB = (cz * d + fy) * d + fx;
    const uint32_t bC = (fz * d + cy) * d + fx;
    const uint32_t bD = (fz * d + fy) * d + fx;

    float2 qA, qB, qC, qD;
    asm volatile("global_load_dwordx2 %0, %1, off sc0" : "=v"(qA) : "v"(g + bA));
    asm volatile("global_load_dwordx2 %0, %1, off sc0" : "=v"(qB) : "v"(g + bB));
    asm volatile("global_load_dwordx2 %0, %1, off sc0" : "=v"(qC) : "v"(g + bC));
    asm volatile("global_load_dwordx2 %0, %1, off sc0" : "=v"(qD) : "v"(g + bD));
    asm volatile("s_waitcnt vmcnt(0)" ::: "memory");
    __builtin_amdgcn_sched_barrier(0);

    const float2 f3 = h2f_bits(qA.x);
    const float2 f0 = xadj ? h2f_bits(qA.y) : f3;
    const float2 f2 = h2f_bits(qB.x);
    const float2 f1 = xadj ? h2f_bits(qB.y) : f2;
    const float2 f7 = h2f_bits(qC.x);
    const float2 f4 = xadj ? h2f_bits(qC.y) : f7;
    const float2 f6 = h2f_bits(qD.x);
    const float2 f5 = xadj ? h2f_bits(qD.y) : f6;
    return lerp8(f0, f1, f2, f3, f4, f5, f6, f7, ox, oy, oz);
}

// --------------------- fp32 table -> fp16 table conversion -----------------
__global__ __launch_bounds__(256)
void convert_table(const float2* __restrict__ t, __half2* __restrict__ th)
{
    const uint32_t i = (blockIdx.x * 256u + threadIdx.x) * 4u;  // 4 entries
    const float4 q0 = *(const float4*)(t + i);       // entries i, i+1
    const float4 q1 = *(const float4*)(t + i + 2);   // entries i+2, i+3
    __half2 h0 = __floats2half2_rn(q0.x, q0.y);
    __half2 h1 = __floats2half2_rn(q0.z, q0.w);
    __half2 h2 = __floats2half2_rn(q1.x, q1.y);
    __half2 h3 = __floats2half2_rn(q1.z, q1.w);
    uint32_t u0, u1, u2, u3;
    __builtin_memcpy(&u0, &h0, 4); __builtin_memcpy(&u1, &h1, 4);
    __builtin_memcpy(&u2, &h2, 4); __builtin_memcpy(&u3, &h3, 4);
    uint4 v; v.x = u0; v.y = u1; v.z = u2; v.w = u3;
    *(uint4*)(th + i) = v;
}

// ----------------------- dense fp16-grid build (levels 0..4) ---------------
__global__ __launch_bounds__(256)
void build_grids(const float2* __restrict__ table, __half2* __restrict__ gridbuf,
                 Params P)
{
    const uint32_t t = blockIdx.x * 256u + threadIdx.x;
    if (t >= P.vcum[NGRID]) return;
    uint32_t l = 0;
    #pragma unroll
    for (int i = 1; i < NGRID; ++i) if (t >= P.vcum[i]) l = i;
    const uint32_t v = t - P.vcum[l];
    const uint32_t d = P.gdim[l];
    const uint32_t vz = v / (d * d);
    const uint32_t r1 = v - vz * d * d;
    const uint32_t vy = r1 / d;
    const uint32_t vx = r1 - vy * d;
    const uint32_t h = ((vx ^ (vy * PR1) ^ (vz * PR2)) & TMASK) + (l << TBITS);
    const float2 e = table[h];
    gridbuf[P.goff[l] + v] = __floats2half2_rn(e.x, e.y);
}

// ---------------- phased gather: fp16 grids + fp16 hash table --------------
__global__ __launch_bounds__(256)
void gather16(const float* __restrict__ x,
              const __half2* __restrict__ th,
              const __half2* __restrict__ gridbuf,
              __half2* __restrict__ stage,
              Params P)
{
    const uint32_t l = blockIdx.x / CHUNKS;     // level-phased for L2 residency
    const uint32_t p = (blockIdx.x % CHUNKS) * 256u + threadIdx.x;

    const float x0 = x[p * 3 + 0];
    const float x1 = x[p * 3 + 1];
    const float x2 = x[p * 3 + 2];

    float2 e;
    if (l < NGRID)
        e = eval_grid_h(x0, x1, x2, P.s[l], gridbuf + P.goff[l], P.gdim[l]);
    else
        e = eval_hash_h(x0, x1, x2, P.s[l], l, th);

    stage[l * NPTS + p] = __floats2half2_rn(e.x, e.y);
}

// ------------- transpose [l][p] -> [p][l], identity order, coalesced -------
__global__ __launch_bounds__(256)
void transpose_kernel(const __half2* __restrict__ stage, float* __restrict__ out)
{
    const uint32_t e = blockIdx.x * 256u + threadIdx.x;  // = p*8 + j
    const uint32_t p = e >> 3;
    const uint32_t j = e & 7u;
    const float2 a = __half22float2(stage[(2u*j)     * NPTS + p]);
    const float2 b = __half22float2(stage[(2u*j + 1) * NPTS + p]);
    vf4 v; v.x = a.x; v.y = a.y; v.z = b.x; v.w = b.y;
    __builtin_nontemporal_store(v, (vf4*)(out + (size_t)e * 4u));
}

// ------------------------- fused fallback (plain C++, fp32) ----------------
__device__ __forceinline__ void load_pair_plain(const float2* __restrict__ t,
                                                uint32_t iF, uint32_t iC,
                                                float2& vF, float2& vC)
{
    const uint32_t lo = iF < iC ? iF : iC;
    const uint32_t hi = iF < iC ? iC : iF;
    if (hi - lo == 1u) {
        const float4 q = *(const float4*)(t + lo);
        if (iF == lo) { vF = make_float2(q.x, q.y); vC = make_float2(q.z, q.w); }
        else          { vF = make_float2(q.z, q.w); vC = make_float2(q.x, q.y); }
    } else {
        vF = t[iF]; vC = t[iC];
    }
}

__global__ __launch_bounds__(256)
void hashenc_fused(const float* __restrict__ x,
                   const float2* __restrict__ table,
                   float2* __restrict__ out,
                   Params P)
{
    const uint32_t tid = blockIdx.x * 256u + threadIdx.x;
    const uint32_t p = tid >> 4;
    const uint32_t l = tid & 15u;

    const float x0 = x[p*3+0], x1 = x[p*3+1], x2 = x[p*3+2];
    const float s  = P.s[l];
    const float sx = x0 * s, sy = x1 * s, sz = x2 * s;
    const float fxf = floorf(sx), fyf = floorf(sy), fzf = floorf(sz);
    const float cxf = ceilf(sx),  cyf = ceilf(sy),  czf = ceilf(sz);
    const float ox = sx - fxf, oy = sy - fyf, oz = sz - fzf;

    const uint32_t fx = (uint32_t)fxf, cx = (uint32_t)cxf;
    const uint32_t Yf = (uint32_t)fyf * PR1,  Yc = (uint32_t)cyf * PR1;
    const uint32_t Zf = (uint32_t)fzf * PR2,  Zc = (uint32_t)czf * PR2;
    const uint32_t base = l << TBITS;

    const uint32_t i0 = ((cx ^ Yc ^ Zc) & TMASK) + base;
    const uint32_t i1 = ((cx ^ Yf ^ Zc) & TMASK) + base;
    const uint32_t i2 = ((fx ^ Yf ^ Zc) & TMASK) + base;
    const uint32_t i3 = ((fx ^ Yc ^ Zc) & TMASK) + base;
    const uint32_t i4 = ((cx ^ Yc ^ Zf) & TMASK) + base;
    const uint32_t i5 = ((cx ^ Yf ^ Zf) & TMASK) + base;
    const uint32_t i6 = ((fx ^ Yf ^ Zf) & TMASK) + base;
    const uint32_t i7 = ((fx ^ Yc ^ Zf) & TMASK) + base;

    float2 f0, f1, f2, f3, f4, f5, f6, f7;
    load_pair_plain(table, i3, i0, f3, f0);
    load_pair_plain(table, i2, i1, f2, f1);
    load_pair_plain(table, i7, i4, f7, f4);
    load_pair_plain(table, i6, i5, f6, f5);
    out[p * 16u + l] = lerp8(f0, f1, f2, f3, f4, f5, f6, f7, ox, oy, oz);
}

extern "C" void kernel_launch(void* const* d_in, const int* in_sizes, int n_in,
                              void* d_out, int out_size, void* d_ws, size_t ws_size,
                              hipStream_t stream) {
    const float*  x     = (const float*)d_in[0];
    const float2* table = (const float2*)d_in[1];

    // SCALINGS: replicate numpy float64 pipeline in identical op order.
    Params P;
    const double growth = exp((log(4096.0) - log(16.0)) / 15.0);
    for (int l = 0; l < NLVL; ++l)
        P.s[l] = (float)floor(16.0 * pow(growth, (double)l));

    uint32_t vtot = 0;
    for (int l = 0; l < NGRID; ++l) {
        const uint32_t d = (uint32_t)P.s[l] + 1u;
        P.gdim[l] = d;
        P.vcum[l] = vtot;
        P.goff[l] = vtot;
        vtot += d * d * d;
    }
    P.vcum[NGRID] = vtot;                            // 533,601 vertices

    // ws: gridbuf_h (~2.1 MiB) | table_h (32 MiB) | stage fp16 (64 MiB)
    const size_t grid_bytes  = (((size_t)vtot * sizeof(__half2)) + 255u) & ~(size_t)255u;
    const size_t tabh_bytes  = (size_t)TSIZE * NLVL * sizeof(__half2);   // 33.5 MB
    const size_t stage_bytes = (size_t)NPTS * NLVL * sizeof(__half2);
    const size_t ws_needed   = grid_bytes + tabh_bytes + stage_bytes;

    if (ws_size >= ws_needed) {
        __half2* gridbuf = (__half2*)d_ws;
        __half2* th      = (__half2*)((char*)d_ws + grid_bytes);
        __half2* stage   = (__half2*)((char*)d_ws + grid_bytes + tabh_bytes);

        dim3 b256(256u);
        hipLaunchKernelGGL(convert_table, dim3(TSIZE * NLVL / 1024u), b256, 0, stream,
                           table, th);
        hipLaunchKernelGGL(build_grids, dim3((vtot + 255u) / 256u), b256, 0, stream,
                           table, gridbuf, P);
        hipLaunchKernelGGL(gather16, dim3(NLVL * CHUNKS), b256, 0, stream,
                           x, th, gridbuf, stage, P);
        hipLaunchKernelGGL(transpose_kernel, dim3(NPTS * 8u / 256u), b256, 0, stream,
                           stage, (float*)d_out);
    } else {
        float2* out = (float2*)d_out;
        hipLaunchKernelGGL(hashenc_fused, dim3(NPTS * NLVL / 256u), dim3(256u), 0, stream,
                           x, table, out, P);
    }
}